// Round 15
// baseline (35.757 us; speedup 1.0000x reference)
//
#include <hip/hip_runtime.h>
#include <math.h>

// N=512, IN_F=128, OUT_F=64, H=4.
// 2-node pipeline:
//  K1 (288 blk x 256): ht rows 2b,2b+1 -> htbT[f][j] bf16 + s1 + s2;
//                      tail blocks pack U,V -> bf16. (r14-proven verbatim)
//  K2 (64 blk x 1024 thr, block = 8 full rows): scores+exp (no max-sub,
//      masked -> exp(-9e15)=0 exactly) -> Es bf16 [rh=h*8+r][512], den via
//      32-lane shfl; num = Es @ htbT^T with B-frags streamed DIRECTLY from
//      global htbT (L2-hot, no LDS stage); c = num*dinv; bf16 U/V epilogue
//      (4-way k-split + LDS psum combine); sigmoid -> out.
// MFMA fragment layout HW-verified r11-r14: A/B row = lane&15, k-slice =
// ks*32+(lane>>4)*8 (8 contig bf16); D row = (lane>>4)*4+q, col = lane&15.

typedef short short8 __attribute__((ext_vector_type(8)));
typedef float f32x4 __attribute__((ext_vector_type(4)));
union CDu { f32x4 v; float f[4]; };

#define MFMA(A,B,C) __builtin_amdgcn_mfma_f32_16x16x32_bf16((A),(B),(C),0,0,0)

__device__ __forceinline__ unsigned pk2(float lo, float hi) {
    return __builtin_amdgcn_perm(__float_as_uint(hi) + 0x8000u,
                                 __float_as_uint(lo) + 0x8000u, 0x07060302u);
}
__device__ __forceinline__ float asf(unsigned u) { return __uint_as_float(u); }

// ---------------- K1 (r14 verbatim) ----------------
__global__ __launch_bounds__(256) void k1(
    const float* __restrict__ h, const float* __restrict__ W,
    const float* __restrict__ a, const float* __restrict__ U,
    const float* __restrict__ V,
    ushort* __restrict__ htbT, float* __restrict__ s1, float* __restrict__ s2p,
    unsigned* __restrict__ Ub, unsigned* __restrict__ Vb)
{
    const int t = threadIdx.x;
    if (blockIdx.x >= 256) {   // weight packing tail
        const int m = (blockIdx.x - 256) * 256 + t;
        const float2* U2 = (const float2*)U;
        const float2* V2 = (const float2*)V;
        #pragma unroll
        for (int k = 0; k < 2; ++k) {
            float2 f = U2[m + k * 8192];
            Ub[m + k * 8192] = pk2(f.x, f.y);
        }
        #pragma unroll
        for (int k = 0; k < 4; ++k) {
            float2 f = V2[m + k * 8192];
            Vb[m + k * 8192] = pk2(f.x, f.y);
        }
        return;
    }
    __shared__ float hsh[2 * 128];
    __shared__ float ash[512];
    __shared__ float hts[2 * 256];
    const int i0 = blockIdx.x * 2;
    if (t < 64)       ((float4*)hsh)[t]      = ((const float4*)(h + i0 * 128))[t];
    else if (t < 192) ((float4*)ash)[t - 64] = ((const float4*)a)[t - 64];
    __syncthreads();

    float acc0 = 0.f, acc1 = 0.f;
    const float4* Wv = (const float4*)(W + t * 128);
    #pragma unroll
    for (int kk = 0; kk < 32; ++kk) {
        float4 w4 = Wv[kk];
        const float* h0 = hsh + kk * 4;
        const float* h1 = hsh + 128 + kk * 4;
        acc0 += w4.x * h0[0] + w4.y * h0[1] + w4.z * h0[2] + w4.w * h0[3];
        acc1 += w4.x * h1[0] + w4.y * h1[1] + w4.z * h1[2] + w4.w * h1[3];
    }
    *(unsigned*)((char*)htbT + t * 1024 + i0 * 2) = pk2(acc0, acc1);
    hts[t]       = acc0;
    hts[256 + t] = acc1;
    __syncthreads();

    if (t < 40) {
        const int rr = t & 1, o = t >> 1;
        const float* x;
        const float* y;
        if (o < 16) { x = hts + rr * 256 + (o >> 2) * 64;  y = ash + (o & 3) * 128; }
        else        { x = hts + rr * 256 + (o - 16) * 64;  y = ash + (o - 16) * 128 + 64; }
        float s = 0.f;
        #pragma unroll
        for (int ff = 0; ff < 64; ++ff) {
            int f = (ff + (t << 3)) & 63;
            s += x[f] * y[f];
        }
        if (o < 16) s1[(i0 + rr) * 16 + (o >> 2) * 4 + (o & 3)] = s;
        else        s2p[(o - 16) * 512 + i0 + rr] = s;
    }
}

// ---------------- K2: fused attention + aggregate + epilogue ----------------
// 64 blocks x 1024 thr (16 waves), block = 8 full output rows.
__global__ __launch_bounds__(1024) void k2(
    const float* __restrict__ h, const int* __restrict__ adj,
    const float* __restrict__ ew, const ushort* __restrict__ htbT,
    const float* __restrict__ s1, const float* __restrict__ s2p,
    const unsigned* __restrict__ Ub, const unsigned* __restrict__ Vb,
    float* __restrict__ out)
{
    __shared__ float s2sh[4 * 512];                // 8 KB [h][j]
    __shared__ float hshK[8 * 128];                // 4 KB own h rows
    __shared__ float s1sh[128];                    // [r][16]
    __shared__ __align__(16) char Es[32 * 1040];   // 32.5 KB bf16 [rh][j], 1040B pitch
    __shared__ float numsh[32 * 68];               // 8.5 KB [rh][f-in-head]
    __shared__ float csh[8 * 256];                 // 8 KB c rows f32
    __shared__ float psum[4 * 2048];               // 32 KB epilogue partials
    __shared__ float den_s[32], dinv[32];

    const int t = threadIdx.x, l = t & 63, w = t >> 6;
    const int i0 = blockIdx.x * 8;

    if (t < 512)      ((float4*)s2sh)[t]       = ((const float4*)s2p)[t];
    else if (t < 768) ((float4*)hshK)[t - 512] = ((const float4*)(h + i0 * 128))[t - 512];
    else if (t < 896) s1sh[t - 768] = s1[(i0 + ((t - 768) >> 4)) * 16 + ((t - 768) & 15)];
    __syncthreads();

    {   // scores + exp -> Es; thread = (rh = t>>5, 16 j at jseg)
        const int rh = t >> 5, jseg = (t & 31) * 16;
        const int r = rh & 7, hh = rh >> 3;
        const float s1v = s1sh[r * 16 + (jseg >> 7) * 4 + hh];
        const int base = (i0 + r) * 512 + jseg;
        float den = 0.f;
        float v[16];
        #pragma unroll
        for (int q = 0; q < 4; ++q) {
            int4   av = *(const int4*)  (adj + base + q * 4);
            float4 wv = *(const float4*)(ew  + base + q * 4);
            const float* sp = s2sh + hh * 512 + jseg + q * 4;
            int   ai[4] = {av.x, av.y, av.z, av.w};
            float wi[4] = {wv.x, wv.y, wv.z, wv.w};
            #pragma unroll
            for (int k = 0; k < 4; ++k) {
                float e = s1v + sp[k];
                e = (e >= 0.f) ? e : 0.2f * e;
                e = (ai[k] > 0) ? e * wi[k] : -9.0e15f;
                float x = __expf(e);      // masked -> exactly 0
                v[q * 4 + k] = x; den += x;
            }
        }
        *(uint4*)(Es + rh * 1040 + jseg * 2) =
            make_uint4(pk2(v[0],v[1]), pk2(v[2],v[3]), pk2(v[4],v[5]), pk2(v[6],v[7]));
        *(uint4*)(Es + rh * 1040 + jseg * 2 + 16) =
            make_uint4(pk2(v[8],v[9]), pk2(v[10],v[11]), pk2(v[12],v[13]), pk2(v[14],v[15]));
        #pragma unroll
        for (int o = 16; o; o >>= 1) den += __shfl_xor(den, o, 64);
        if ((l & 31) == 0) den_s[rh] = den;
    }
    __syncthreads();
    if (t < 32) dinv[t] = 1.f / den_s[t];

    {   // num = Es @ htbT^T; wave w owns f-tile w; B-frags from GLOBAL htbT
        const int mt = w >> 3;
        const ushort* gB = htbT + (w * 16 + (l & 15)) * 512 + (l >> 4) * 8;
        const char* aRow = Es + (mt * 16 + (l & 15)) * 1040 + (l >> 4) * 16;
        f32x4 acc = {0.f, 0.f, 0.f, 0.f};
        #pragma unroll
        for (int ks = 0; ks < 16; ++ks) {
            short8 Af = *(const short8*)(aRow + ks * 64);
            short8 Bf = *(const short8*)(gB + ks * 32);
            acc = MFMA(Af, Bf, acc);
        }
        CDu cd; cd.v = acc;
        const int sel = (w >> 2) & 1;
        #pragma unroll
        for (int q = 0; q < 4; ++q) {
            int rloc = (l >> 4) * 4 + q;
            if ((rloc >> 3) == sel)   // head-matching quadrant
                numsh[(mt * 16 + rloc) * 68 + (w & 3) * 16 + (l & 15)] = cd.f[q];
        }
    }
    __syncthreads();

    #pragma unroll
    for (int p = 0; p < 2; ++p) {   // c = num * dinv
        int idx = p * 1024 + t, r = idx >> 8, hf = idx & 255;
        int rh = (hf >> 6) * 8 + r;
        csh[idx] = numsh[rh * 68 + (hf & 63)] * dinv[rh];
    }
    __syncthreads();

    {   // epilogue: thread = (col = t&255, k-grp = t>>8); bf16 U/V streams
        const int col = t & 255, grp = t >> 8;
        float acc[8] = {0.f,0.f,0.f,0.f,0.f,0.f,0.f,0.f};
        if (grp < 2) {
            const uint4* Up = (const uint4*)(Ub + col * 64 + grp * 32);
            #pragma unroll
            for (int b4 = 0; b4 < 8; ++b4) {
                uint4 uv = Up[b4];
                unsigned ua[4] = {uv.x, uv.y, uv.z, uv.w};
                #pragma unroll
                for (int e = 0; e < 4; ++e) {
                    int k = grp * 64 + b4 * 8 + e * 2;
                    float lo = asf(ua[e] << 16), hi = asf(ua[e] & 0xffff0000u);
                    #pragma unroll
                    for (int r = 0; r < 8; ++r)
                        acc[r] += lo * hshK[r * 128 + k] + hi * hshK[r * 128 + k + 1];
                }
            }
        } else {
            const uint4* Vp = (const uint4*)(Vb + col * 128 + (grp - 2) * 64);
            #pragma unroll
            for (int b4 = 0; b4 < 16; ++b4) {
                uint4 vv = Vp[b4];
                unsigned va[4] = {vv.x, vv.y, vv.z, vv.w};
                #pragma unroll
                for (int e = 0; e < 4; ++e) {
                    int k = (grp - 2) * 128 + b4 * 8 + e * 2;
                    float lo = asf(va[e] << 16), hi = asf(va[e] & 0xffff0000u);
                    #pragma unroll
                    for (int r = 0; r < 8; ++r)
                        acc[r] += lo * csh[r * 256 + k] + hi * csh[r * 256 + k + 1];
                }
            }
        }
        #pragma unroll
        for (int r = 0; r < 8; ++r) psum[grp * 2048 + r * 256 + col] = acc[r];
    }
    __syncthreads();
    #pragma unroll
    for (int p = 0; p < 2; ++p) {
        int idx = p * 1024 + t;
        float x = psum[idx] + psum[2048 + idx] + psum[4096 + idx] + psum[6144 + idx];
        out[i0 * 256 + idx] = 1.f / (1.f + __expf(-x));
    }
}

extern "C" void kernel_launch(void* const* d_in, const int* in_sizes, int n_in,
                              void* d_out, int out_size, void* d_ws, size_t ws_size,
                              hipStream_t stream) {
    const float* h   = (const float*)d_in[0];
    const int*   adj = (const int*)d_in[1];
    const float* ew  = (const float*)d_in[2];
    const float* W   = (const float*)d_in[3];
    const float* a   = (const float*)d_in[4];
    const float* U   = (const float*)d_in[5];
    const float* V   = (const float*)d_in[6];
    float* out = (float*)d_out;

    ushort*  htbT = (ushort*)d_ws;                 // 256*512 bf16 = 256 KB
    float*   s1   = (float*)(htbT + 256 * 512);    // 512*16
    float*   s2p  = s1 + 512 * 16;                 // 4*512
    unsigned* Ub  = (unsigned*)(s2p + 2048);       // 16384 u32
    unsigned* Vb  = Ub + 16384;                    // 32768 u32

    k1<<<288, 256, 0, stream>>>(h, W, a, U, V, htbT, s1, s2p, Ub, Vb);
    k2<<<64, 1024, 0, stream>>>(h, adj, ew, htbT, s1, s2p, Ub, Vb, out);
}

// Round 16
// 25.445 us; speedup vs baseline: 1.4053x; 1.4053x over previous
//
#include <hip/hip_runtime.h>
#include <math.h>

// N=512, IN_F=128, OUT_F=64, H=4.
// 3-node pipeline, latency-optimized content (round-14 proven: 24.6 us):
//  K1 (288 blk x 256): ht rows 2b,2b+1 -> htbT[f][j] bf16 j-pair + s1 + s2;
//                      tail blocks pack U,V -> bf16.
//  K2 (256 blk = 64 i-tiles x 4 j-chunks, 512 thr): scores+exp (no max-sub,
//      masked -> exp(-9e15) = 0 exactly), Es bf16 (rh = h*8+r), denominators
//      via 16-lane shfl, num = Es @ htT via MFMA -> partial num/den per chunk.
//  K3 (256 blk x 512): c = (sum_q num)/(sum_q den), bf16 U/V epilogue, sigmoid.
// MFMA fragment layout HW-verified r11/r12: A/B row = lane&15, k-slice =
// ks*32+(lane>>4)*8 (8 contig bf16); D row = (lane>>4)*4+q, col = lane&15.

typedef short short8 __attribute__((ext_vector_type(8)));
typedef float f32x4 __attribute__((ext_vector_type(4)));
union CDu { f32x4 v; float f[4]; };

#define MFMA(A,B,C) __builtin_amdgcn_mfma_f32_16x16x32_bf16((A),(B),(C),0,0,0)

__device__ __forceinline__ unsigned pk2(float lo, float hi) {
    return __builtin_amdgcn_perm(__float_as_uint(hi) + 0x8000u,
                                 __float_as_uint(lo) + 0x8000u, 0x07060302u);
}
__device__ __forceinline__ float asf(unsigned u) { return __uint_as_float(u); }

// ---------------- K1 ----------------
__global__ __launch_bounds__(256) void k1(
    const float* __restrict__ h, const float* __restrict__ W,
    const float* __restrict__ a, const float* __restrict__ U,
    const float* __restrict__ V,
    ushort* __restrict__ htbT, float* __restrict__ s1, float* __restrict__ s2p,
    unsigned* __restrict__ Ub, unsigned* __restrict__ Vb)
{
    const int t = threadIdx.x;
    if (blockIdx.x >= 256) {   // weight packing tail
        const int m = (blockIdx.x - 256) * 256 + t;
        const float2* U2 = (const float2*)U;
        const float2* V2 = (const float2*)V;
        #pragma unroll
        for (int k = 0; k < 2; ++k) {
            float2 f = U2[m + k * 8192];
            Ub[m + k * 8192] = pk2(f.x, f.y);
        }
        #pragma unroll
        for (int k = 0; k < 4; ++k) {
            float2 f = V2[m + k * 8192];
            Vb[m + k * 8192] = pk2(f.x, f.y);
        }
        return;
    }
    __shared__ float hsh[2 * 128];
    __shared__ float ash[512];
    __shared__ float hts[2 * 256];
    const int i0 = blockIdx.x * 2;
    if (t < 64)       ((float4*)hsh)[t]      = ((const float4*)(h + i0 * 128))[t];
    else if (t < 192) ((float4*)ash)[t - 64] = ((const float4*)a)[t - 64];
    __syncthreads();

    float acc0 = 0.f, acc1 = 0.f;
    const float4* Wv = (const float4*)(W + t * 128);
    #pragma unroll
    for (int kk = 0; kk < 32; ++kk) {
        float4 w4 = Wv[kk];
        const float* h0 = hsh + kk * 4;
        const float* h1 = hsh + 128 + kk * 4;
        acc0 += w4.x * h0[0] + w4.y * h0[1] + w4.z * h0[2] + w4.w * h0[3];
        acc1 += w4.x * h1[0] + w4.y * h1[1] + w4.z * h1[2] + w4.w * h1[3];
    }
    // transposed bf16 store: htbT[feature t][j-pair i0/2]
    *(unsigned*)((char*)htbT + t * 1024 + i0 * 2) = pk2(acc0, acc1);
    hts[t]       = acc0;
    hts[256 + t] = acc1;
    __syncthreads();

    if (t < 40) {
        const int rr = t & 1, o = t >> 1;
        const float* x;
        const float* y;
        if (o < 16) { x = hts + rr * 256 + (o >> 2) * 64;  y = ash + (o & 3) * 128; }
        else        { x = hts + rr * 256 + (o - 16) * 64;  y = ash + (o - 16) * 128 + 64; }
        float s = 0.f;
        #pragma unroll
        for (int ff = 0; ff < 64; ++ff) {
            int f = (ff + (t << 3)) & 63;
            s += x[f] * y[f];
        }
        if (o < 16) s1[(i0 + rr) * 16 + (o >> 2) * 4 + (o & 3)] = s;
        else        s2p[(o - 16) * 512 + i0 + rr] = s;
    }
}

// ---------------- K2: partial attention x aggregate ----------------
__global__ __launch_bounds__(512) void k2(
    const int* __restrict__ adj, const float* __restrict__ ew,
    const ushort* __restrict__ htbT, const float* __restrict__ s1,
    const float* __restrict__ s2p,
    float* __restrict__ nump, float* __restrict__ denp)
{
    __shared__ __align__(16) char hTl[256 * 272];  // bf16 [f][j-chunk], 272B pitch
    __shared__ __align__(16) char Es[32 * 272];    // bf16 [rh = h*8+r][j]
    __shared__ float s2sh[512];                    // [h][128]
    __shared__ float s1sh[128];                    // [r][16]
    const int t = threadIdx.x, l = t & 63, w = t >> 6;
    const int it = blockIdx.x >> 2, q = blockIdx.x & 3;
    const int i0 = it * 8, jg = q * 128;

    #pragma unroll
    for (int p = 0; p < 8; ++p) {   // stage htbT chunk, coalesced uint4
        int lin = p * 512 + t, row = lin >> 4, jseg = (lin & 15) * 8;
        uint4 v = *(const uint4*)(htbT + row * 512 + jg + jseg);
        *(uint4*)(hTl + row * 272 + jseg * 2) = v;
    }
    s2sh[t] = s2p[(t >> 7) * 512 + jg + (t & 127)];
    if (t < 128) s1sh[t] = s1[(i0 + (t >> 4)) * 16 + (t & 15)];
    __syncthreads();

    {   // scores + exp -> Es; thread = (rh = t>>4, 8 consecutive j)
        const int rh = t >> 4, j8 = (t & 15) * 8;
        const int r = rh & 7, hh = rh >> 3;
        const float s1v = s1sh[r * 16 + q * 4 + hh];
        const int base = (i0 + r) * 512 + jg + j8;
        int4   a0 = *(const int4*)(adj + base), a1 = *(const int4*)(adj + base + 4);
        float4 w0 = *(const float4*)(ew + base), w1 = *(const float4*)(ew + base + 4);
        float v[8];
        const float* sp = s2sh + hh * 128 + j8;
        int   ai[8] = {a0.x,a0.y,a0.z,a0.w,a1.x,a1.y,a1.z,a1.w};
        float wi[8] = {w0.x,w0.y,w0.z,w0.w,w1.x,w1.y,w1.z,w1.w};
        float den = 0.f;
        #pragma unroll
        for (int k = 0; k < 8; ++k) {
            float e = s1v + sp[k];
            e = (e >= 0.f) ? e : 0.2f * e;
            e = (ai[k] > 0) ? e * wi[k] : -9.0e15f;
            v[k] = __expf(e);           // masked -> exactly 0
            den += v[k];
        }
        *(uint4*)(Es + rh * 272 + j8 * 2) =
            make_uint4(pk2(v[0],v[1]), pk2(v[2],v[3]), pk2(v[4],v[5]), pk2(v[6],v[7]));
        #pragma unroll
        for (int o = 1; o < 16; o <<= 1) den += __shfl_xor(den, o, 64);
        if ((l & 15) == 0) denp[(q * 64 + it) * 32 + rh] = den;
    }
    __syncthreads();

    {   // num = Es @ hTl^T slices; wave w -> pairs p = 2w, 2w+1
        #pragma unroll
        for (int pp = 0; pp < 2; ++pp) {
            const int p = w * 2 + pp, mt = p >> 3, ntl = p & 7;
            const int nt = mt * 8 + ntl;
            f32x4 acc = {0.f, 0.f, 0.f, 0.f};
            #pragma unroll
            for (int ks = 0; ks < 4; ++ks) {
                const int kb = ks * 32 + (l >> 4) * 8;
                short8 Af = *(const short8*)(Es + (mt * 16 + (l & 15)) * 272 + kb * 2);
                short8 Bf = *(const short8*)(hTl + (nt * 16 + (l & 15)) * 272 + kb * 2);
                acc = MFMA(Af, Bf, acc);
            }
            CDu cd; cd.v = acc;
            const int fcol = ntl * 16 + (l & 15);   // f within mt's 128-block
            const int fh = fcol >> 6;
            #pragma unroll
            for (int q4 = 0; q4 < 4; ++q4) {
                const int rloc = (l >> 4) * 4 + q4;
                if ((rloc >> 3) == fh) {            // head-matching quadrant
                    const int rh = mt * 16 + rloc;
                    nump[((q * 64 + it) * 32 + rh) * 64 + (fcol & 63)] = cd.f[q4];
                }
            }
        }
    }
}

// ---------------- K3: combine + epilogue ----------------
__global__ __launch_bounds__(512) void k3(
    const float* __restrict__ h, const float* __restrict__ nump,
    const float* __restrict__ denp, const unsigned* __restrict__ Ub,
    const unsigned* __restrict__ Vb, float* __restrict__ out)
{
    __shared__ float hsh[2 * 128];
    __shared__ float csh[2 * 256];
    __shared__ float psum[4 * 256];
    const int t = threadIdx.x;
    const int i0 = blockIdx.x * 2;
    const int it = i0 >> 3, rbase = i0 & 7;

    if (t < 64) ((float4*)hsh)[t] = ((const float4*)(h + i0 * 128))[t];
    {   // c = (sum_q num) / (sum_q den)
        const int r = t >> 8, hf = t & 255, hh = hf >> 6, fp = hf & 63;
        const int rh = hh * 8 + rbase + r;
        float num = 0.f, den = 0.f;
        #pragma unroll
        for (int qq = 0; qq < 4; ++qq) {
            num += nump[((qq * 64 + it) * 32 + rh) * 64 + fp];
            den += denp[(qq * 64 + it) * 32 + rh];
        }
        csh[r * 256 + hf] = num / den;
    }
    __syncthreads();

    {   // bf16 epilogue, K-half split
        const int half = t >> 8, col = t & 255;
        float acc0 = 0.f, acc1 = 0.f;
        const uint4* Up = (const uint4*)(Ub + col * 64 + half * 32);
        #pragma unroll
        for (int b4 = 0; b4 < 8; ++b4) {
            uint4 uv = Up[b4];
            unsigned ua[4] = {uv.x, uv.y, uv.z, uv.w};
            #pragma unroll
            for (int e = 0; e < 4; ++e) {
                const int k = half * 64 + b4 * 8 + e * 2;
                float ulo = asf(ua[e] << 16), uhi = asf(ua[e] & 0xffff0000u);
                acc0 += ulo * hsh[k]       + uhi * hsh[k + 1];
                acc1 += ulo * hsh[128 + k] + uhi * hsh[128 + k + 1];
            }
        }
        const uint4* Vp = (const uint4*)(Vb + col * 128 + half * 64);
        #pragma unroll
        for (int b4 = 0; b4 < 16; ++b4) {
            uint4 vv = Vp[b4];
            unsigned va[4] = {vv.x, vv.y, vv.z, vv.w};
            #pragma unroll
            for (int e = 0; e < 4; ++e) {
                const int k = half * 128 + b4 * 8 + e * 2;
                float vlo = asf(va[e] << 16), vhi = asf(va[e] & 0xffff0000u);
                acc0 += vlo * csh[k]       + vhi * csh[k + 1];
                acc1 += vlo * csh[256 + k] + vhi * csh[256 + k + 1];
            }
        }
        psum[(half * 2 + 0) * 256 + col] = acc0;
        psum[(half * 2 + 1) * 256 + col] = acc1;
    }
    __syncthreads();
    {
        const int r = t >> 8, col = t & 255;
        float x = psum[r * 256 + col] + psum[(2 + r) * 256 + col];
        out[(i0 + r) * 256 + col] = 1.f / (1.f + __expf(-x));
    }
}

extern "C" void kernel_launch(void* const* d_in, const int* in_sizes, int n_in,
                              void* d_out, int out_size, void* d_ws, size_t ws_size,
                              hipStream_t stream) {
    const float* h   = (const float*)d_in[0];
    const int*   adj = (const int*)d_in[1];
    const float* ew  = (const float*)d_in[2];
    const float* W   = (const float*)d_in[3];
    const float* a   = (const float*)d_in[4];
    const float* U   = (const float*)d_in[5];
    const float* V   = (const float*)d_in[6];
    float* out = (float*)d_out;

    ushort*  htbT = (ushort*)d_ws;                 // 256*512 bf16 = 256 KB
    float*   s1   = (float*)(htbT + 256 * 512);    // 512*16
    float*   s2p  = s1 + 512 * 16;                 // 4*512
    unsigned* Ub  = (unsigned*)(s2p + 2048);       // 16384 u32
    unsigned* Vb  = Ub + 16384;                    // 32768 u32
    float*   nump = (float*)(Vb + 32768);          // 4*64*32*64 f32 = 2 MB
    float*   denp = nump + 4 * 64 * 32 * 64;       // 4*64*32 f32

    k1<<<288, 256, 0, stream>>>(h, W, a, U, V, htbT, s1, s2p, Ub, Vb);
    k2<<<256, 512, 0, stream>>>(adj, ew, htbT, s1, s2p, nump, denp);
    k3<<<256, 512, 0, stream>>>(h, nump, denp, Ub, Vb, out);
}